// Round 2
// baseline (5214.495 us; speedup 1.0000x reference)
//
#include <hip/hip_runtime.h>
#include <hip/hip_bf16.h>
#include <math.h>

#define T_TOK 2048   // B*N tokens
#define DMODEL 768
#define NHEADS 12
#define HDIM 64
#define NEXP 8
#define EHID 2048
#define NLAYER 4

__device__ __forceinline__ float siluf(float x){ return x / (1.0f + expf(-x)); }
__device__ __forceinline__ float geluf(float x){ return 0.5f*x*(1.0f+erff(x*0.70710678118654752f)); }

// ---------------- patchify: (B,3,256,256) -> (T, 768) with feature order (c,ph,pw)
__global__ void k_patchify(const float* __restrict__ x, float* __restrict__ xp){
  int idx = blockIdx.x*256 + threadIdx.x;
  int t = idx / 768, f = idx % 768;
  int b = t >> 8, n = t & 255;
  int gh = n >> 4, gw = n & 15;
  int c = f >> 8, r = f & 255;
  int ph = r >> 4, pw = r & 15;
  xp[idx] = x[(((size_t)(b*3 + c)*256) + gh*16 + ph)*256 + gw*16 + pw];
}

// ---------------- timestep + task/modality conditioning -> c (8,768)
__global__ __launch_bounds__(256) void k_cond(const float* __restrict__ t,
    const int* __restrict__ task_id, const int* __restrict__ mod_id,
    const float* __restrict__ t1w, const float* __restrict__ t1b,
    const float* __restrict__ t2w, const float* __restrict__ t2b,
    const float* __restrict__ task_tab, const float* __restrict__ mod_tab,
    float* __restrict__ c){
  __shared__ float te[256];
  __shared__ float tm[768];
  int b = blockIdx.x, tid = threadIdx.x;
  float tv = t[b];
  int i = tid & 127;
  float freq = expf(-9.210340371976184f * (float)i / 128.0f);
  float arg = tv * freq;
  te[tid] = (tid < 128) ? cosf(arg) : sinf(arg);
  __syncthreads();
  for (int d = tid; d < 768; d += 256){
    float acc = t1b[d];
    for (int k = 0; k < 256; k++) acc += te[k]*t1w[k*768+d];
    tm[d] = siluf(acc);
  }
  __syncthreads();
  for (int d = tid; d < 768; d += 256){
    float acc = t2b[d];
    for (int k = 0; k < 768; k++) acc += tm[k]*t2w[k*768+d];
    c[b*768+d] = acc + task_tab[task_id[b]*768+d] + mod_tab[mod_id[b]*768+d];
  }
}

// ---------------- out[b][n] = bias[n] + sum_k silu(c[b][k]) * W[k][n]   (adaLN / final mod)
__global__ __launch_bounds__(256) void k_mod(const float* __restrict__ c,
    const float* __restrict__ W, const float* __restrict__ bias,
    float* __restrict__ out, int N){
  __shared__ float sc[768];
  int b = blockIdx.y, tid = threadIdx.x;
  for (int k = tid; k < 768; k += 256) sc[k] = siluf(c[b*768+k]);
  __syncthreads();
  int n = blockIdx.x*256 + tid;
  float acc = bias[n];
  for (int k = 0; k < 768; k++) acc += sc[k]*W[(size_t)k*N + n];
  out[(size_t)b*N + n] = acc;
}

// ---------------- rmsnorm + modulate: out = rms(x)*w*(1+scale[b]) + shift[b]
__global__ __launch_bounds__(256) void k_rms_mod(const float* __restrict__ x,
    float* __restrict__ out, const float* __restrict__ w,
    const float* __restrict__ shift, const float* __restrict__ scale, int mstride){
  __shared__ float red[256];
  int t = blockIdx.x, tid = threadIdx.x;
  float v0 = x[t*768 + tid], v1 = x[t*768 + 256 + tid], v2 = x[t*768 + 512 + tid];
  red[tid] = v0*v0 + v1*v1 + v2*v2;
  __syncthreads();
  for (int s2 = 128; s2 > 0; s2 >>= 1){ if (tid < s2) red[tid] += red[tid+s2]; __syncthreads(); }
  float r = rsqrtf(red[0]/768.0f + 1e-6f);
  int b = t >> 8;
  const float* sh = shift + (size_t)b*mstride;
  const float* scp = scale + (size_t)b*mstride;
  out[t*768 + tid]       = v0*r*w[tid]    *(1.0f+scp[tid])     + sh[tid];
  out[t*768 + 256 + tid] = v1*r*w[tid+256]*(1.0f+scp[tid+256]) + sh[tid+256];
  out[t*768 + 512 + tid] = v2*r*w[tid+512]*(1.0f+scp[tid+512]) + sh[tid+512];
}

// ---------------- q/k head-rms + 2D RoPE, in place on qkv (T,2304)
__global__ __launch_bounds__(256) void k_qkv_prep(float* __restrict__ qkv,
    const float* __restrict__ qnw, const float* __restrict__ knw){
  int t = blockIdx.x;
  int wid = threadIdx.x >> 6, lane = threadIdx.x & 63;
  int n = t & 255;
  float phc = (float)(n >> 4), pwc = (float)(n & 15);
  int j = (lane & 31) >> 1;
  float freq = expf(-9.210340371976184f * (float)j / 16.0f);
  float ang = ((lane < 32) ? phc : pwc) * freq;
  float ca = cosf(ang), sa = sinf(ang);
  for (int r = wid; r < 24; r += 4){
    int isK = (r >= 12);
    int h = isK ? r - 12 : r;
    float* p = qkv + (size_t)t*2304 + (isK ? 768 : 0) + h*64 + lane;
    float v = *p;
    float ss = v*v;
    #pragma unroll
    for (int off = 32; off; off >>= 1) ss += __shfl_xor(ss, off);
    float rr = rsqrtf(ss/64.0f + 1e-6f);
    float w = isK ? knw[lane] : qnw[lane];
    float xn = v*rr*w;
    float partner = __shfl_xor(xn, 1);
    float xr = (lane & 1) ? partner : -partner;
    *p = xn*ca + xr*sa;
  }
}

// ---------------- attention: one block per (b,h,row). 256 keys.
__global__ __launch_bounds__(256) void k_attn(const float* __restrict__ qkv,
    float* __restrict__ out){
  __shared__ float sq[64];
  __shared__ float s[256];
  __shared__ float red[256];
  int n = blockIdx.x, h = blockIdx.y, b = blockIdx.z;
  int tid = threadIdx.x;
  const float* qp = qkv + ((size_t)(b*256+n))*2304 + h*64;
  if (tid < 64) sq[tid] = qp[tid];
  __syncthreads();
  const float* kp = qkv + ((size_t)(b*256+tid))*2304 + 768 + h*64;
  float acc = 0.f;
  #pragma unroll 8
  for (int d = 0; d < 64; d++) acc += sq[d]*kp[d];
  acc *= 0.125f;
  s[tid] = acc; red[tid] = acc;
  __syncthreads();
  for (int st = 128; st; st >>= 1){ if (tid < st) red[tid] = fmaxf(red[tid], red[tid+st]); __syncthreads(); }
  float mx = red[0];
  __syncthreads();
  float p = expf(s[tid]-mx);
  s[tid] = p; red[tid] = p;
  __syncthreads();
  for (int st = 128; st; st >>= 1){ if (tid < st) red[tid] += red[tid+st]; __syncthreads(); }
  float inv = 1.0f/red[0];
  __syncthreads();
  int d = tid & 63, c4 = tid >> 6;
  const float* vp = qkv + ((size_t)(b*256 + c4*64))*2304 + 1536 + h*64 + d;
  float oacc = 0.f;
  #pragma unroll 4
  for (int m = 0; m < 64; m++) oacc += s[c4*64+m] * vp[(size_t)m*2304];
  __syncthreads();
  red[tid] = oacc;
  __syncthreads();
  if (tid < 64){
    float o = (red[tid] + red[tid+64] + red[tid+128] + red[tid+192]) * inv;
    out[((size_t)(b*256+n))*768 + h*64 + tid] = o;
  }
}

// ---------------- router: logits, top-2, gates, expert lists
__global__ __launch_bounds__(256) void k_router(const float* __restrict__ hh,
    const float* __restrict__ rw, int* __restrict__ counts,
    int* __restrict__ list, float* __restrict__ gate_slot){
  int wid = threadIdx.x >> 6, lane = threadIdx.x & 63;
  int t = blockIdx.x*4 + wid;
  float acc[8] = {0,0,0,0,0,0,0,0};
  for (int k = lane; k < 768; k += 64){
    float a = hh[t*768 + k];
    #pragma unroll
    for (int e = 0; e < 8; e++) acc[e] += a * rw[k*8 + e];
  }
  #pragma unroll
  for (int e = 0; e < 8; e++){
    #pragma unroll
    for (int off = 32; off; off >>= 1) acc[e] += __shfl_xor(acc[e], off);
  }
  if (lane == 0){
    float v1 = -1e30f, v2 = -1e30f; int e1 = 0, e2 = 0;
    #pragma unroll
    for (int e = 0; e < 8; e++){
      float v = acc[e];
      if (v > v1){ v2 = v1; e2 = e1; v1 = v; e1 = e; }
      else if (v > v2){ v2 = v; e2 = e; }
    }
    float g1 = 1.0f/(1.0f+expf(v2-v1));
    float g2 = 1.0f - g1;
    int p1 = atomicAdd(&counts[e1], 1); list[e1*2048 + p1] = t*2;
    int p2 = atomicAdd(&counts[e2], 1); list[e2*2048 + p2] = t*2+1;
    gate_slot[t*2] = g1; gate_slot[t*2+1] = g2;
  }
}

// ---------------- dense fp32 GEMM, 64x64x16 tile, 4x4 microtile
// EPI: 0=none 1=+bias 2=gelu(+bias) 3=C = C + gate[b]*acc (gated residual, in place)
template<int EPI>
__global__ __launch_bounds__(256) void gemm_f32(
    const float* __restrict__ A, const float* __restrict__ B, float* __restrict__ C,
    int M, int N, int K, const float* __restrict__ bias,
    const float* __restrict__ gate, int gstride){
  __shared__ float As[16][64];
  __shared__ float Bs[16][64];
  int tid = threadIdx.x;
  int m0 = blockIdx.y*64, n0 = blockIdx.x*64;
  int am = tid & 63, ak = (tid >> 6) << 2;
  int bn = tid & 63, bk = tid >> 6;
  int tx = tid & 15, ty = tid >> 4;
  float acc[4][4] = {};
  const float* Arow = A + (size_t)(m0 + am)*K;
  for (int k0 = 0; k0 < K; k0 += 16){
    float4 av = *(const float4*)(Arow + k0 + ak);
    As[ak][am] = av.x; As[ak+1][am] = av.y; As[ak+2][am] = av.z; As[ak+3][am] = av.w;
    #pragma unroll
    for (int kk = 0; kk < 4; kk++)
      Bs[bk + kk*4][bn] = B[(size_t)(k0 + bk + kk*4)*N + n0 + bn];
    __syncthreads();
    #pragma unroll
    for (int k = 0; k < 16; k++){
      float a[4], bb[4];
      #pragma unroll
      for (int i = 0; i < 4; i++) a[i] = As[k][ty*4+i];
      #pragma unroll
      for (int jj = 0; jj < 4; jj++) bb[jj] = Bs[k][tx*4+jj];
      #pragma unroll
      for (int i = 0; i < 4; i++)
        #pragma unroll
        for (int jj = 0; jj < 4; jj++) acc[i][jj] += a[i]*bb[jj];
    }
    __syncthreads();
  }
  #pragma unroll
  for (int i = 0; i < 4; i++){
    int m = m0 + ty*4 + i;
    #pragma unroll
    for (int jj = 0; jj < 4; jj++){
      int nn = n0 + tx*4 + jj;
      float v = acc[i][jj];
      if (EPI == 1) v += bias[nn];
      if (EPI == 2){ v += bias[nn]; v = geluf(v); }
      if (EPI == 3) v = C[(size_t)m*N + nn] + gate[(size_t)(m >> 8)*gstride + nn]*v;
      C[(size_t)m*N + nn] = v;
    }
  }
}

// ---------------- grouped MoE GEMM 1: h_mid[slot] = silu(hh_g @ w1) * (hh_g @ w3)
__global__ __launch_bounds__(256) void moe_gemm1(
    const float* __restrict__ hh, const float* __restrict__ w1,
    const float* __restrict__ w3, const int* __restrict__ counts,
    const int* __restrict__ list, float* __restrict__ h_mid, int layer){
  int e = blockIdx.y >> 5, mt = blockIdx.y & 31;
  int count = counts[e];
  if (mt*64 >= count) return;
  int n0 = blockIdx.x*64;
  const float* B1 = w1 + ((size_t)(layer*8 + e))*768*2048;
  const float* B3 = w3 + ((size_t)(layer*8 + e))*768*2048;
  __shared__ float As[16][64];
  __shared__ float B1s[16][64];
  __shared__ float B3s[16][64];
  __shared__ int slotArr[64];
  __shared__ int tokArr[64];
  int tid = threadIdx.x;
  if (tid < 64){
    int ml = mt*64 + tid;
    int s = (ml < count) ? list[e*2048 + ml] : -1;
    slotArr[tid] = s;
    tokArr[tid] = (s < 0) ? 0 : (s >> 1);
  }
  __syncthreads();
  int am = tid & 63, ak = (tid >> 6) << 2;
  int atok = tokArr[am];
  const float* Arow = hh + (size_t)atok*768;
  int bn = tid & 63, bk = tid >> 6;
  int tx = tid & 15, ty = tid >> 4;
  float acc1[4][4] = {}, acc3[4][4] = {};
  for (int k0 = 0; k0 < 768; k0 += 16){
    float4 av = *(const float4*)(Arow + k0 + ak);
    As[ak][am] = av.x; As[ak+1][am] = av.y; As[ak+2][am] = av.z; As[ak+3][am] = av.w;
    #pragma unroll
    for (int kk = 0; kk < 4; kk++){
      B1s[bk + kk*4][bn] = B1[(size_t)(k0 + bk + kk*4)*2048 + n0 + bn];
      B3s[bk + kk*4][bn] = B3[(size_t)(k0 + bk + kk*4)*2048 + n0 + bn];
    }
    __syncthreads();
    #pragma unroll
    for (int k = 0; k < 16; k++){
      float a[4], b1[4], b3[4];
      #pragma unroll
      for (int i = 0; i < 4; i++) a[i] = As[k][ty*4+i];
      #pragma unroll
      for (int jj = 0; jj < 4; jj++){ b1[jj] = B1s[k][tx*4+jj]; b3[jj] = B3s[k][tx*4+jj]; }
      #pragma unroll
      for (int i = 0; i < 4; i++)
        #pragma unroll
        for (int jj = 0; jj < 4; jj++){ acc1[i][jj] += a[i]*b1[jj]; acc3[i][jj] += a[i]*b3[jj]; }
    }
    __syncthreads();
  }
  #pragma unroll
  for (int i = 0; i < 4; i++){
    int s = slotArr[ty*4 + i];
    if (s < 0) continue;
    float* outp = h_mid + (size_t)s*2048 + n0 + tx*4;
    #pragma unroll
    for (int jj = 0; jj < 4; jj++){
      float v1 = acc1[i][jj], v3 = acc3[i][jj];
      outp[jj] = siluf(v1)*v3;
    }
  }
}

// ---------------- grouped MoE GEMM 2: y_slot[slot] = gate[slot] * (h_mid[slot] @ w2)
__global__ __launch_bounds__(256) void moe_gemm2(
    const float* __restrict__ h_mid, const float* __restrict__ w2,
    const int* __restrict__ counts, const int* __restrict__ list,
    float* __restrict__ y_slot, const float* __restrict__ gate_slot, int layer){
  int e = blockIdx.y >> 5, mt = blockIdx.y & 31;
  int count = counts[e];
  if (mt*64 >= count) return;
  int n0 = blockIdx.x*64;
  const float* B = w2 + ((size_t)(layer*8 + e))*2048*768;
  __shared__ float As[16][64];
  __shared__ float Bs[16][64];
  __shared__ int slotArr[64];
  int tid = threadIdx.x;
  if (tid < 64){
    int ml = mt*64 + tid;
    slotArr[tid] = (ml < count) ? list[e*2048 + ml] : -1;
  }
  __syncthreads();
  int am = tid & 63, ak = (tid >> 6) << 2;
  int as = slotArr[am]; if (as < 0) as = 0;
  const float* Arow = h_mid + (size_t)as*2048;
  int bn = tid & 63, bk = tid >> 6;
  int tx = tid & 15, ty = tid >> 4;
  float acc[4][4] = {};
  for (int k0 = 0; k0 < 2048; k0 += 16){
    float4 av = *(const float4*)(Arow + k0 + ak);
    As[ak][am] = av.x; As[ak+1][am] = av.y; As[ak+2][am] = av.z; As[ak+3][am] = av.w;
    #pragma unroll
    for (int kk = 0; kk < 4; kk++)
      Bs[bk + kk*4][bn] = B[(size_t)(k0 + bk + kk*4)*768 + n0 + bn];
    __syncthreads();
    #pragma unroll
    for (int k = 0; k < 16; k++){
      float a[4], bb[4];
      #pragma unroll
      for (int i = 0; i < 4; i++) a[i] = As[k][ty*4+i];
      #pragma unroll
      for (int jj = 0; jj < 4; jj++) bb[jj] = Bs[k][tx*4+jj];
      #pragma unroll
      for (int i = 0; i < 4; i++)
        #pragma unroll
        for (int jj = 0; jj < 4; jj++) acc[i][jj] += a[i]*bb[jj];
    }
    __syncthreads();
  }
  #pragma unroll
  for (int i = 0; i < 4; i++){
    int s = slotArr[ty*4+i];
    if (s < 0) continue;
    float g = gate_slot[s];
    float* outp = y_slot + (size_t)s*768 + n0 + tx*4;
    #pragma unroll
    for (int jj = 0; jj < 4; jj++) outp[jj] = g*acc[i][jj];
  }
}

// ---------------- combine MoE: x += gp[b] * (y_slot[2t] + y_slot[2t+1])
__global__ void k_combine(float* __restrict__ x, const float* __restrict__ y_slot,
                          const float* __restrict__ gp){
  int idx = blockIdx.x*256 + threadIdx.x;
  int t = idx / 768, d = idx % 768;
  int b = t >> 8;
  x[idx] += gp[(size_t)b*4608 + d]*(y_slot[(size_t)(t*2)*768 + d] + y_slot[(size_t)(t*2+1)*768 + d]);
}

extern "C" void kernel_launch(void* const* d_in, const int* in_sizes, int n_in,
                              void* d_out, int out_size, void* d_ws, size_t ws_size,
                              hipStream_t stream){
  const float* x       = (const float*)d_in[0];
  const float* t       = (const float*)d_in[1];
  const int*   task_id = (const int*)d_in[2];
  const int*   mod_id  = (const int*)d_in[3];
  const float* pe1_w   = (const float*)d_in[4];
  const float* pe1_b   = (const float*)d_in[5];
  const float* pe2_w   = (const float*)d_in[6];
  const float* pe2_b   = (const float*)d_in[7];
  const float* t1_w    = (const float*)d_in[8];
  const float* t1_b    = (const float*)d_in[9];
  const float* t2_w    = (const float*)d_in[10];
  const float* t2_b    = (const float*)d_in[11];
  const float* task_tab= (const float*)d_in[12];
  const float* mod_tab = (const float*)d_in[13];
  const float* qkv_w   = (const float*)d_in[14];
  const float* proj_w  = (const float*)d_in[15];
  const float* qn_w    = (const float*)d_in[16];
  const float* kn_w    = (const float*)d_in[17];
  const float* n1_w    = (const float*)d_in[18];
  const float* n2_w    = (const float*)d_in[19];
  const float* ada_w   = (const float*)d_in[20];
  const float* ada_b   = (const float*)d_in[21];
  const float* rt_w    = (const float*)d_in[22];
  const float* w1      = (const float*)d_in[23];
  const float* w2      = (const float*)d_in[24];
  const float* w3      = (const float*)d_in[25];
  const float* fn_w    = (const float*)d_in[26];
  const float* fada_w  = (const float*)d_in[27];
  const float* fada_b  = (const float*)d_in[28];
  const float* fp_w    = (const float*)d_in[29];
  const float* fp_b    = (const float*)d_in[30];

  float* ws = (float*)d_ws;
  float* h_mid   = ws;  ws += (size_t)4096*2048;   // also reused as xp/pemid scratch pre-loop
  float* xbuf    = ws;  ws += (size_t)2048*768;
  float* hh      = ws;  ws += (size_t)2048*768;
  float* qkv     = ws;  ws += (size_t)2048*2304;
  float* attn    = ws;  ws += (size_t)2048*768;
  float* y_slot  = ws;  ws += (size_t)4096*768;
  float* cbuf    = ws;  ws += 8*768;
  float* mod     = ws;  ws += 8*4608;
  float* fmod    = ws;  ws += 8*1536;
  float* gate_slot = ws; ws += 4096;
  int* counts = (int*)ws; ws += 8;
  int* list   = (int*)ws; ws += 8*2048;

  float* xp    = h_mid;                       // (T,768) pre-loop scratch
  float* pemid = h_mid + (size_t)2048*768;    // (T,128) pre-loop scratch

  // patch embed
  k_patchify<<<6144, 256, 0, stream>>>(x, xp);
  gemm_f32<2><<<dim3(2, 32), 256, 0, stream>>>(xp, pe1_w, pemid, 2048, 128, 768, pe1_b, nullptr, 0);
  gemm_f32<1><<<dim3(12, 32), 256, 0, stream>>>(pemid, pe2_w, xbuf, 2048, 768, 128, pe2_b, nullptr, 0);
  // conditioning
  k_cond<<<8, 256, 0, stream>>>(t, task_id, mod_id, t1_w, t1_b, t2_w, t2_b, task_tab, mod_tab, cbuf);

  for (int l = 0; l < NLAYER; l++){
    k_mod<<<dim3(18, 8), 256, 0, stream>>>(cbuf, ada_w + (size_t)l*768*4608, ada_b + (size_t)l*4608, mod, 4608);
    // attention branch
    k_rms_mod<<<2048, 256, 0, stream>>>(xbuf, hh, n1_w + l*768, mod + 0, mod + 768, 4608);
    gemm_f32<0><<<dim3(36, 32), 256, 0, stream>>>(hh, qkv_w + (size_t)l*768*2304, qkv, 2048, 2304, 768, nullptr, nullptr, 0);
    k_qkv_prep<<<2048, 256, 0, stream>>>(qkv, qn_w + l*64, kn_w + l*64);
    k_attn<<<dim3(256, 12, 8), 256, 0, stream>>>(qkv, attn);
    gemm_f32<3><<<dim3(12, 32), 256, 0, stream>>>(attn, proj_w + (size_t)l*768*768, xbuf, 2048, 768, 768, nullptr, mod + 2*768, 4608);
    // MoE branch
    k_rms_mod<<<2048, 256, 0, stream>>>(xbuf, hh, n2_w + l*768, mod + 3*768, mod + 4*768, 4608);
    hipMemsetAsync(counts, 0, 8*sizeof(int), stream);
    k_router<<<512, 256, 0, stream>>>(hh, rt_w + (size_t)l*768*8, counts, list, gate_slot);
    moe_gemm1<<<dim3(32, 256), 256, 0, stream>>>(hh, w1, w3, counts, list, h_mid, l);
    moe_gemm2<<<dim3(12, 256), 256, 0, stream>>>(h_mid, w2, counts, list, y_slot, gate_slot, l);
    k_combine<<<6144, 256, 0, stream>>>(xbuf, y_slot, mod + 5*768);
  }

  // final layer: write fp32 directly to d_out
  k_mod<<<dim3(6, 8), 256, 0, stream>>>(cbuf, fada_w, fada_b, fmod, 1536);
  k_rms_mod<<<2048, 256, 0, stream>>>(xbuf, hh, fn_w, fmod + 0, fmod + 768, 1536);
  gemm_f32<1><<<dim3(12, 32), 256, 0, stream>>>(hh, fp_w, (float*)d_out, 2048, 768, 768, fp_b, nullptr, 0);
}

// Round 4
// 3823.345 us; speedup vs baseline: 1.3639x; 1.3639x over previous
//
#include <hip/hip_runtime.h>
#include <hip/hip_bf16.h>
#include <math.h>

typedef __bf16 bf16x8 __attribute__((ext_vector_type(8)));
typedef float f32x4 __attribute__((ext_vector_type(4)));

__device__ __forceinline__ float siluf(float x){ return x / (1.0f + expf(-x)); }
__device__ __forceinline__ float geluf(float x){ return 0.5f*x*(1.0f+erff(x*0.70710678118654752f)); }

// exact truncation split: f = hi + lo with hi,lo bf16 (trunc), |f-(hi+lo)| <~ 2^-16 |f|
__device__ __forceinline__ void split1(float f, unsigned short& hi, unsigned short& lo){
  union { float f; unsigned int u; } a; a.f = f;
  unsigned int h = a.u & 0xffff0000u;
  hi = (unsigned short)(h >> 16);
  union { unsigned int u; float f; } hf; hf.u = h;
  union { float f; unsigned int u; } l; l.f = f - hf.f;
  lo = (unsigned short)(l.u >> 16);
}
// split a k-adjacent pair (f0=even k, f1=odd k) into packed u32s (lo16=even, hi16=odd)
__device__ __forceinline__ void split2(float f0, float f1, unsigned int& hi, unsigned int& lo){
  union { float f; unsigned int u; } a, b; a.f = f0; b.f = f1;
  unsigned int h0 = a.u & 0xffff0000u, h1 = b.u & 0xffff0000u;
  hi = (h0 >> 16) | h1;
  union { unsigned int u; float f; } hf0, hf1; hf0.u = h0; hf1.u = h1;
  union { float f; unsigned int u; } l0, l1; l0.f = f0 - hf0.f; l1.f = f1 - hf1.f;
  lo = (l0.u >> 16) | (l1.u & 0xffff0000u);
}

// ---------------- patchify -> split bf16 (T,768), feature order (c,ph,pw)
__global__ void k_patchify(const float* __restrict__ x,
                           unsigned short* __restrict__ xh, unsigned short* __restrict__ xl){
  int idx = blockIdx.x*256 + threadIdx.x;
  int t = idx / 768, f = idx % 768;
  int b = t >> 8, n = t & 255;
  int gh = n >> 4, gw = n & 15;
  int c = f >> 8, r = f & 255;
  int ph = r >> 4, pw = r & 15;
  float v = x[(((size_t)(b*3 + c)*256) + gh*16 + ph)*256 + gw*16 + pw];
  unsigned short h, l; split1(v, h, l);
  xh[idx] = h; xl[idx] = l;
}

// ---------------- timestep + task/modality conditioning -> c (8,768)
__global__ __launch_bounds__(256) void k_cond(const float* __restrict__ t,
    const int* __restrict__ task_id, const int* __restrict__ mod_id,
    const float* __restrict__ t1w, const float* __restrict__ t1b,
    const float* __restrict__ t2w, const float* __restrict__ t2b,
    const float* __restrict__ task_tab, const float* __restrict__ mod_tab,
    float* __restrict__ c){
  __shared__ float te[256];
  __shared__ float tm[768];
  int b = blockIdx.x, tid = threadIdx.x;
  float tv = t[b];
  int i = tid & 127;
  float freq = expf(-9.210340371976184f * (float)i / 128.0f);
  float arg = tv * freq;
  te[tid] = (tid < 128) ? cosf(arg) : sinf(arg);
  __syncthreads();
  for (int d = tid; d < 768; d += 256){
    float acc = t1b[d];
    for (int k = 0; k < 256; k++) acc += te[k]*t1w[k*768+d];
    tm[d] = siluf(acc);
  }
  __syncthreads();
  for (int d = tid; d < 768; d += 256){
    float acc = t2b[d];
    for (int k = 0; k < 768; k++) acc += tm[k]*t2w[k*768+d];
    c[b*768+d] = acc + task_tab[task_id[b]*768+d] + mod_tab[mod_id[b]*768+d];
  }
}

// ---------------- out[b][n] = bias[n] + sum_k silu(c[b][k]) * W[k][n]
__global__ __launch_bounds__(256) void k_mod(const float* __restrict__ c,
    const float* __restrict__ W, const float* __restrict__ bias,
    float* __restrict__ out, int N){
  __shared__ float sc[768];
  int b = blockIdx.y, tid = threadIdx.x;
  for (int k = tid; k < 768; k += 256) sc[k] = siluf(c[b*768+k]);
  __syncthreads();
  int n = blockIdx.x*256 + tid;
  float acc = bias[n];
  for (int k = 0; k < 768; k++) acc += sc[k]*W[(size_t)k*N + n];
  out[(size_t)b*N + n] = acc;
}

// ---------------- rmsnorm + modulate -> fp32 + split bf16
__global__ __launch_bounds__(256) void k_rms_mod(const float* __restrict__ x,
    float* __restrict__ out, unsigned short* __restrict__ oh, unsigned short* __restrict__ ol,
    const float* __restrict__ w,
    const float* __restrict__ shift, const float* __restrict__ scale, int mstride){
  __shared__ float red[256];
  int t = blockIdx.x, tid = threadIdx.x;
  float v0 = x[t*768 + tid], v1 = x[t*768 + 256 + tid], v2 = x[t*768 + 512 + tid];
  red[tid] = v0*v0 + v1*v1 + v2*v2;
  __syncthreads();
  for (int s2 = 128; s2 > 0; s2 >>= 1){ if (tid < s2) red[tid] += red[tid+s2]; __syncthreads(); }
  float r = rsqrtf(red[0]/768.0f + 1e-6f);
  int b = t >> 8;
  const float* sh = shift + (size_t)b*mstride;
  const float* scp = scale + (size_t)b*mstride;
  float o0 = v0*r*w[tid]    *(1.0f+scp[tid])     + sh[tid];
  float o1 = v1*r*w[tid+256]*(1.0f+scp[tid+256]) + sh[tid+256];
  float o2 = v2*r*w[tid+512]*(1.0f+scp[tid+512]) + sh[tid+512];
  out[t*768 + tid] = o0; out[t*768 + 256 + tid] = o1; out[t*768 + 512 + tid] = o2;
  unsigned short h, l;
  split1(o0, h, l); oh[t*768 + tid]       = h; ol[t*768 + tid]       = l;
  split1(o1, h, l); oh[t*768 + 256 + tid] = h; ol[t*768 + 256 + tid] = l;
  split1(o2, h, l); oh[t*768 + 512 + tid] = h; ol[t*768 + 512 + tid] = l;
}

// ---------------- q/k head-rms + 2D RoPE, in place on qkv (T,2304) fp32
__global__ __launch_bounds__(256) void k_qkv_prep(float* __restrict__ qkv,
    const float* __restrict__ qnw, const float* __restrict__ knw){
  int t = blockIdx.x;
  int wid = threadIdx.x >> 6, lane = threadIdx.x & 63;
  int n = t & 255;
  float phc = (float)(n >> 4), pwc = (float)(n & 15);
  int j = (lane & 31) >> 1;
  float freq = expf(-9.210340371976184f * (float)j / 16.0f);
  float ang = ((lane < 32) ? phc : pwc) * freq;
  float ca = cosf(ang), sa = sinf(ang);
  for (int r = wid; r < 24; r += 4){
    int isK = (r >= 12);
    int h = isK ? r - 12 : r;
    float* p = qkv + (size_t)t*2304 + (isK ? 768 : 0) + h*64 + lane;
    float v = *p;
    float ss = v*v;
    #pragma unroll
    for (int off = 32; off; off >>= 1) ss += __shfl_xor(ss, off);
    float rr = rsqrtf(ss/64.0f + 1e-6f);
    float w = isK ? knw[lane] : qnw[lane];
    float xn = v*rr*w;
    float partner = __shfl_xor(xn, 1);
    float xr = (lane & 1) ? partner : -partner;
    *p = xn*ca + xr*sa;
  }
}

// ---------------- attention: one block per (b,h,row). 256 keys. split bf16 out.
__global__ __launch_bounds__(256) void k_attn(const float* __restrict__ qkv,
    unsigned short* __restrict__ oh, unsigned short* __restrict__ ol){
  __shared__ float sq[64];
  __shared__ float s[256];
  __shared__ float red[256];
  int n = blockIdx.x, h = blockIdx.y, b = blockIdx.z;
  int tid = threadIdx.x;
  const float* qp = qkv + ((size_t)(b*256+n))*2304 + h*64;
  if (tid < 64) sq[tid] = qp[tid];
  __syncthreads();
  const float* kp = qkv + ((size_t)(b*256+tid))*2304 + 768 + h*64;
  float acc = 0.f;
  #pragma unroll 8
  for (int d = 0; d < 64; d++) acc += sq[d]*kp[d];
  acc *= 0.125f;
  s[tid] = acc; red[tid] = acc;
  __syncthreads();
  for (int st = 128; st; st >>= 1){ if (tid < st) red[tid] = fmaxf(red[tid], red[tid+st]); __syncthreads(); }
  float mx = red[0];
  __syncthreads();
  float p = expf(s[tid]-mx);
  s[tid] = p; red[tid] = p;
  __syncthreads();
  for (int st = 128; st; st >>= 1){ if (tid < st) red[tid] += red[tid+st]; __syncthreads(); }
  float inv = 1.0f/red[0];
  __syncthreads();
  int d = tid & 63, c4 = tid >> 6;
  const float* vp = qkv + ((size_t)(b*256 + c4*64))*2304 + 1536 + h*64 + d;
  float oacc = 0.f;
  #pragma unroll 4
  for (int m = 0; m < 64; m++) oacc += s[c4*64+m] * vp[(size_t)m*2304];
  __syncthreads();
  red[tid] = oacc;
  __syncthreads();
  if (tid < 64){
    float o = (red[tid] + red[tid+64] + red[tid+128] + red[tid+192]) * inv;
    unsigned short hh, ll; split1(o, hh, ll);
    oh[((size_t)(b*256+n))*768 + h*64 + tid] = hh;
    ol[((size_t)(b*256+n))*768 + h*64 + tid] = ll;
  }
}

// ---------------- router (fp32 hh)
__global__ __launch_bounds__(256) void k_router(const float* __restrict__ hh,
    const float* __restrict__ rw, int* __restrict__ counts,
    int* __restrict__ list, float* __restrict__ gate_slot){
  int wid = threadIdx.x >> 6, lane = threadIdx.x & 63;
  int t = blockIdx.x*4 + wid;
  float acc[8] = {0,0,0,0,0,0,0,0};
  for (int k = lane; k < 768; k += 64){
    float a = hh[t*768 + k];
    #pragma unroll
    for (int e = 0; e < 8; e++) acc[e] += a * rw[k*8 + e];
  }
  #pragma unroll
  for (int e = 0; e < 8; e++){
    #pragma unroll
    for (int off = 32; off; off >>= 1) acc[e] += __shfl_xor(acc[e], off);
  }
  if (lane == 0){
    float v1 = -1e30f, v2 = -1e30f; int e1 = 0, e2 = 0;
    #pragma unroll
    for (int e = 0; e < 8; e++){
      float v = acc[e];
      if (v > v1){ v2 = v1; e2 = e1; v1 = v; e1 = e; }
      else if (v > v2){ v2 = v; e2 = e; }
    }
    float g1 = 1.0f/(1.0f+expf(v2-v1));
    float g2 = 1.0f - g1;
    int p1 = atomicAdd(&counts[e1], 1); list[e1*2048 + p1] = t*2;
    int p2 = atomicAdd(&counts[e2], 1); list[e2*2048 + p2] = t*2+1;
    gate_slot[t*2] = g1; gate_slot[t*2+1] = g2;
  }
}

// =================== split-bf16 MFMA GEMM (3-pass), 128x128 tile, 4 waves @64x64
// A: pre-split (Ahi,Alo) row-major (M,K). B: fp32 (K,N), split during LDS stage.
// EPI: 0 ->f32, 1 +bias->f32, 2 +bias,gelu->split bf16, 3 C += gate*acc (f32 in place)
#define LDK 40
template<int EPI>
__global__ __launch_bounds__(256) void gemm_split(
    const unsigned short* __restrict__ Ahi, const unsigned short* __restrict__ Alo,
    const float* __restrict__ B,
    float* __restrict__ C, unsigned short* __restrict__ Chi, unsigned short* __restrict__ Clo,
    int N, int K,
    const float* __restrict__ bias, const float* __restrict__ gate, int gstride){
  __shared__ unsigned short AsH[128*LDK], AsL[128*LDK];
  __shared__ unsigned short BsH[128*LDK], BsL[128*LDK];
  int tid = threadIdx.x;
  int m0 = blockIdx.y*128, n0 = blockIdx.x*128;
  int lane = tid & 63, wid = tid >> 6;
  int wr = wid >> 1, wc = wid & 1;
  int lr = lane & 15, lg = lane >> 4;
  int ar = tid & 127, ah = tid >> 7;
  int bn = tid & 127, bh = tid >> 7;
  size_t aoff = (size_t)(m0 + ar)*K + ah*16;
  f32x4 acc[4][4] = {};
  for (int k0 = 0; k0 < K; k0 += 32){
    { const uint4* ph = (const uint4*)(Ahi + aoff + k0);
      const uint4* pl = (const uint4*)(Alo + aoff + k0);
      uint4* qh = (uint4*)&AsH[ar*LDK + ah*16];
      uint4* ql = (uint4*)&AsL[ar*LDK + ah*16];
      qh[0] = ph[0]; qh[1] = ph[1]; ql[0] = pl[0]; ql[1] = pl[1]; }
    { const float* bp = B + (size_t)(k0 + bh*16)*N + n0 + bn;
      unsigned int* qh = (unsigned int*)&BsH[bn*LDK + bh*16];
      unsigned int* ql = (unsigned int*)&BsL[bn*LDK + bh*16];
      #pragma unroll
      for (int m2 = 0; m2 < 8; m2++){
        unsigned int h, l;
        split2(bp[(size_t)(2*m2)*N], bp[(size_t)(2*m2+1)*N], h, l);
        qh[m2] = h; ql[m2] = l;
      }
    }
    __syncthreads();
    bf16x8 aH[4], aL[4];
    #pragma unroll
    for (int mf = 0; mf < 4; mf++){
      aH[mf] = *(const bf16x8*)&AsH[(wr*64 + mf*16 + lr)*LDK + lg*8];
      aL[mf] = *(const bf16x8*)&AsL[(wr*64 + mf*16 + lr)*LDK + lg*8];
    }
    #pragma unroll
    for (int nf = 0; nf < 4; nf++){
      bf16x8 bH = *(const bf16x8*)&BsH[(wc*64 + nf*16 + lr)*LDK + lg*8];
      bf16x8 bL = *(const bf16x8*)&BsL[(wc*64 + nf*16 + lr)*LDK + lg*8];
      #pragma unroll
      for (int mf = 0; mf < 4; mf++){
        acc[mf][nf] = __builtin_amdgcn_mfma_f32_16x16x32_bf16(aH[mf], bH, acc[mf][nf], 0, 0, 0);
        acc[mf][nf] = __builtin_amdgcn_mfma_f32_16x16x32_bf16(aH[mf], bL, acc[mf][nf], 0, 0, 0);
        acc[mf][nf] = __builtin_amdgcn_mfma_f32_16x16x32_bf16(aL[mf], bH, acc[mf][nf], 0, 0, 0);
      }
    }
    __syncthreads();
  }
  #pragma unroll
  for (int mf = 0; mf < 4; mf++){
    #pragma unroll
    for (int nf = 0; nf < 4; nf++){
      #pragma unroll
      for (int r = 0; r < 4; r++){
        int m = m0 + wr*64 + mf*16 + lg*4 + r;
        int n = n0 + wc*64 + nf*16 + lr;
        float v = acc[mf][nf][r];
        if (EPI == 1){ C[(size_t)m*N + n] = v + bias[n]; }
        else if (EPI == 2){
          unsigned short h, l; split1(geluf(v + bias[n]), h, l);
          Chi[(size_t)m*N + n] = h; Clo[(size_t)m*N + n] = l;
        }
        else if (EPI == 3){ C[(size_t)m*N + n] += gate[(size_t)(m >> 8)*gstride + n]*v; }
        else { C[(size_t)m*N + n] = v; }
      }
    }
  }
}

// =================== MoE grouped GEMM 1 (split): h_mid[slot] = silu(A@w1)*(A@w3)
__global__ __launch_bounds__(256) void moe_gemm1_split(
    const unsigned short* __restrict__ Ahi, const unsigned short* __restrict__ Alo,
    const float* __restrict__ w1, const float* __restrict__ w3,
    const int* __restrict__ counts, const int* __restrict__ list,
    unsigned short* __restrict__ mh, unsigned short* __restrict__ ml, int layer){
  int e = blockIdx.y >> 4, mt = blockIdx.y & 15;
  int count = counts[e];
  if (mt*128 >= count) return;
  __shared__ unsigned short AsH[128*LDK], AsL[128*LDK];
  __shared__ unsigned short B1H[128*LDK], B1L[128*LDK];
  __shared__ unsigned short B3H[128*LDK], B3L[128*LDK];
  __shared__ int slotArr[128];
  int tid = threadIdx.x;
  int n0 = blockIdx.x*128;
  const float* B1 = w1 + ((size_t)(layer*8 + e))*768*2048;
  const float* B3 = w3 + ((size_t)(layer*8 + e))*768*2048;
  if (tid < 128){
    int ml2 = mt*128 + tid;
    slotArr[tid] = (ml2 < count) ? list[e*2048 + ml2] : -1;
  }
  __syncthreads();
  int lane = tid & 63, wid = tid >> 6;
  int wr = wid >> 1, wc = wid & 1;
  int lr = lane & 15, lg = lane >> 4;
  int ar = tid & 127, ah = tid >> 7;
  int bn = tid & 127, bh = tid >> 7;
  int s0 = slotArr[ar]; int tok = (s0 < 0) ? 0 : (s0 >> 1);
  size_t aoff = (size_t)tok*768 + ah*16;
  f32x4 acc1[4][4] = {}, acc3[4][4] = {};
  for (int k0 = 0; k0 < 768; k0 += 32){
    { const uint4* ph = (const uint4*)(Ahi + aoff + k0);
      const uint4* pl = (const uint4*)(Alo + aoff + k0);
      uint4* qh = (uint4*)&AsH[ar*LDK + ah*16];
      uint4* ql = (uint4*)&AsL[ar*LDK + ah*16];
      qh[0] = ph[0]; qh[1] = ph[1]; ql[0] = pl[0]; ql[1] = pl[1]; }
    { const float* bp1 = B1 + (size_t)(k0 + bh*16)*2048 + n0 + bn;
      const float* bp3 = B3 + (size_t)(k0 + bh*16)*2048 + n0 + bn;
      unsigned int* q1h = (unsigned int*)&B1H[bn*LDK + bh*16];
      unsigned int* q1l = (unsigned int*)&B1L[bn*LDK + bh*16];
      unsigned int* q3h = (unsigned int*)&B3H[bn*LDK + bh*16];
      unsigned int* q3l = (unsigned int*)&B3L[bn*LDK + bh*16];
      #pragma unroll
      for (int m2 = 0; m2 < 8; m2++){
        unsigned int h, l;
        split2(bp1[(size_t)(2*m2)*2048], bp1[(size_t)(2*m2+1)*2048], h, l);
        q1h[m2] = h; q1l[m2] = l;
        split2(bp3[(size_t)(2*m2)*2048], bp3[(size_t)(2*m2+1)*2048], h, l);
        q3h[m2] = h; q3l[m2] = l;
      }
    }
    __syncthreads();
    bf16x8 aH[4], aL[4];
    #pragma unroll
    for (int mf = 0; mf < 4; mf++){
      aH[mf] = *(const bf16x8*)&AsH[(wr*64 + mf*16 + lr)*LDK + lg*8];
      aL[mf] = *(const bf16x8*)&AsL[(wr*64 + mf*16 + lr)*LDK + lg*8];
    }
    #pragma unroll
    for (int nf = 0; nf < 4; nf++){
      bf16x8 b1h = *(const bf16x8*)&B1H[(wc*64 + nf*16 + lr)*LDK + lg*8];
      bf16x8 b1l = *(const bf16x8*)&B1L[(wc*64 + nf*16 + lr)*LDK + lg*8];
      bf16x8 b3h = *(const bf16x8*)&B3H[(wc*64 + nf*16 + lr)*LDK + lg*8];
      bf16x8 b3l = *(const bf16x8*)&B3L[(wc*64 + nf*16 + lr)*LDK + lg*8];
      #pragma unroll
      for (int mf = 0; mf < 4; mf++){
        acc1[mf][nf] = __builtin_amdgcn_mfma_f32_16x16x32_bf16(aH[mf], b1h, acc1[mf][nf], 0, 0, 0);
        acc1[mf][nf] = __builtin_amdgcn_mfma_f32_16x16x32_bf16(aH[mf], b1l, acc1[mf][nf], 0, 0, 0);
        acc1[mf][nf] = __builtin_amdgcn_mfma_f32_16x16x32_bf16(aL[mf], b1h, acc1[mf][nf], 0, 0, 0);
        acc3[mf][nf] = __builtin_amdgcn_mfma_f32_16x16x32_bf16(aH[mf], b3h, acc3[mf][nf], 0, 0, 0);
        acc3[mf][nf] = __builtin_amdgcn_mfma_f32_16x16x32_bf16(aH[mf], b3l, acc3[mf][nf], 0, 0, 0);
        acc3[mf][nf] = __builtin_amdgcn_mfma_f32_16x16x32_bf16(aL[mf], b3h, acc3[mf][nf], 0, 0, 0);
      }
    }
    __syncthreads();
  }
  #pragma unroll
  for (int mf = 0; mf < 4; mf++){
    #pragma unroll
    for (int nf = 0; nf < 4; nf++){
      #pragma unroll
      for (int r = 0; r < 4; r++){
        int row = wr*64 + mf*16 + lg*4 + r;
        int sl = slotArr[row];
        if (sl < 0) continue;
        int n = n0 + wc*64 + nf*16 + lr;
        float v = siluf(acc1[mf][nf][r]) * acc3[mf][nf][r];
        unsigned short h, l; split1(v, h, l);
        mh[(size_t)sl*2048 + n] = h; ml[(size_t)sl*2048 + n] = l;
      }
    }
  }
}

// =================== MoE grouped GEMM 2 (split): y_slot[slot] = gate[slot]*(h_mid[slot]@w2)
__global__ __launch_bounds__(256) void moe_gemm2_split(
    const unsigned short* __restrict__ Ahi, const unsigned short* __restrict__ Alo,
    const float* __restrict__ w2,
    const int* __restrict__ counts, const int* __restrict__ list,
    float* __restrict__ y_slot, const float* __restrict__ gate_slot, int layer){
  int e = blockIdx.y >> 4, mt = blockIdx.y & 15;
  int count = counts[e];
  if (mt*128 >= count) return;
  __shared__ unsigned short AsH[128*LDK], AsL[128*LDK];
  __shared__ unsigned short BsH[128*LDK], BsL[128*LDK];
  __shared__ int slotArr[128];
  int tid = threadIdx.x;
  int n0 = blockIdx.x*128;
  const float* B = w2 + ((size_t)(layer*8 + e))*2048*768;
  if (tid < 128){
    int ml2 = mt*128 + tid;
    slotArr[tid] = (ml2 < count) ? list[e*2048 + ml2] : -1;
  }
  __syncthreads();
  int lane = tid & 63, wid = tid >> 6;
  int wr = wid >> 1, wc = wid & 1;
  int lr = lane & 15, lg = lane >> 4;
  int ar = tid & 127, ah = tid >> 7;
  int bn = tid & 127, bh = tid >> 7;
  int s0 = slotArr[ar]; int arow = (s0 < 0) ? 0 : s0;
  size_t aoff = (size_t)arow*2048 + ah*16;
  f32x4 acc[4][4] = {};
  for (int k0 = 0; k0 < 2048; k0 += 32){
    { const uint4* ph = (const uint4*)(Ahi + aoff + k0);
      const uint4* pl = (const uint4*)(Alo + aoff + k0);
      uint4* qh = (uint4*)&AsH[ar*LDK + ah*16];
      uint4* ql = (uint4*)&AsL[ar*LDK + ah*16];
      qh[0] = ph[0]; qh[1] = ph[1]; ql[0] = pl[0]; ql[1] = pl[1]; }
    { const float* bp = B + (size_t)(k0 + bh*16)*768 + n0 + bn;
      unsigned int* qh = (unsigned int*)&BsH[bn*LDK + bh*16];
      unsigned int* ql = (unsigned int*)&BsL[bn*LDK + bh*16];
      #pragma unroll
      for (int m2 = 0; m2 < 8; m2++){
        unsigned int h, l;
        split2(bp[(size_t)(2*m2)*768], bp[(size_t)(2*m2+1)*768], h, l);
        qh[m2] = h; ql[m2] = l;
      }
    }
    __syncthreads();
    bf16x8 aH[4], aL[4];
    #pragma unroll
    for (int mf = 0; mf < 4; mf++){
      aH[mf] = *(const bf16x8*)&AsH[(wr*64 + mf*16 + lr)*LDK + lg*8];
      aL[mf] = *(const bf16x8*)&AsL[(wr*64 + mf*16 + lr)*LDK + lg*8];
    }
    #pragma unroll
    for (int nf = 0; nf < 4; nf++){
      bf16x8 bH = *(const bf16x8*)&BsH[(wc*64 + nf*16 + lr)*LDK + lg*8];
      bf16x8 bL = *(const bf16x8*)&BsL[(wc*64 + nf*16 + lr)*LDK + lg*8];
      #pragma unroll
      for (int mf = 0; mf < 4; mf++){
        acc[mf][nf] = __builtin_amdgcn_mfma_f32_16x16x32_bf16(aH[mf], bH, acc[mf][nf], 0, 0, 0);
        acc[mf][nf] = __builtin_amdgcn_mfma_f32_16x16x32_bf16(aH[mf], bL, acc[mf][nf], 0, 0, 0);
        acc[mf][nf] = __builtin_amdgcn_mfma_f32_16x16x32_bf16(aL[mf], bH, acc[mf][nf], 0, 0, 0);
      }
    }
    __syncthreads();
  }
  #pragma unroll
  for (int mf = 0; mf < 4; mf++){
    #pragma unroll
    for (int nf = 0; nf < 4; nf++){
      #pragma unroll
      for (int r = 0; r < 4; r++){
        int row = wr*64 + mf*16 + lg*4 + r;
        int sl = slotArr[row];
        if (sl < 0) continue;
        int n = n0 + wc*64 + nf*16 + lr;
        y_slot[(size_t)sl*768 + n] = gate_slot[sl]*acc[mf][nf][r];
      }
    }
  }
}

// ---------------- combine MoE: x += gp[b] * (y_slot[2t] + y_slot[2t+1])
__global__ void k_combine(float* __restrict__ x, const float* __restrict__ y_slot,
                          const float* __restrict__ gp){
  int idx = blockIdx.x*256 + threadIdx.x;
  int t = idx / 768, d = idx % 768;
  int b = t >> 8;
  x[idx] += gp[(size_t)b*4608 + d]*(y_slot[(size_t)(t*2)*768 + d] + y_slot[(size_t)(t*2+1)*768 + d]);
}

extern "C" void kernel_launch(void* const* d_in, const int* in_sizes, int n_in,
                              void* d_out, int out_size, void* d_ws, size_t ws_size,
                              hipStream_t stream){
  const float* x       = (const float*)d_in[0];
  const float* t       = (const float*)d_in[1];
  const int*   task_id = (const int*)d_in[2];
  const int*   mod_id  = (const int*)d_in[3];
  const float* pe1_w   = (const float*)d_in[4];
  const float* pe1_b   = (const float*)d_in[5];
  const float* pe2_w   = (const float*)d_in[6];
  const float* pe2_b   = (const float*)d_in[7];
  const float* t1_w    = (const float*)d_in[8];
  const float* t1_b    = (const float*)d_in[9];
  const float* t2_w    = (const float*)d_in[10];
  const float* t2_b    = (const float*)d_in[11];
  const float* task_tab= (const float*)d_in[12];
  const float* mod_tab = (const float*)d_in[13];
  const float* qkv_w   = (const float*)d_in[14];
  const float* proj_w  = (const float*)d_in[15];
  const float* qn_w    = (const float*)d_in[16];
  const float* kn_w    = (const float*)d_in[17];
  const float* n1_w    = (const float*)d_in[18];
  const float* n2_w    = (const float*)d_in[19];
  const float* ada_w   = (const float*)d_in[20];
  const float* ada_b   = (const float*)d_in[21];
  const float* rt_w    = (const float*)d_in[22];
  const float* w1      = (const float*)d_in[23];
  const float* w2      = (const float*)d_in[24];
  const float* w3      = (const float*)d_in[25];
  const float* fn_w    = (const float*)d_in[26];
  const float* fada_w  = (const float*)d_in[27];
  const float* fada_b  = (const float*)d_in[28];
  const float* fp_w    = (const float*)d_in[29];
  const float* fp_b    = (const float*)d_in[30];

  float* ws = (float*)d_ws;
  float* xbuf    = ws;  ws += (size_t)2048*768;
  float* hh      = ws;  ws += (size_t)2048*768;
  float* qkv     = ws;  ws += (size_t)2048*2304;
  float* y_slot  = ws;  ws += (size_t)4096*768;
  float* cbuf    = ws;  ws += 8*768;
  float* mod     = ws;  ws += 8*4608;
  float* fmod    = ws;  ws += 8*1536;
  float* gate_slot = ws; ws += 4096;
  int* counts = (int*)ws; ws += 8;
  int* list   = (int*)ws; ws += 8*2048;
  ws += 8;
  unsigned short* us = (unsigned short*)ws;
  unsigned short* hh_h   = us; us += (size_t)2048*768;
  unsigned short* hh_l   = us; us += (size_t)2048*768;
  unsigned short* hm_h   = us; us += (size_t)4096*2048;
  unsigned short* hm_l   = us; us += (size_t)4096*2048;
  unsigned short* attn_h = us; us += (size_t)2048*768;
  unsigned short* attn_l = us; us += (size_t)2048*768;
  // pre-loop scratch aliased onto h_mid (only used before layer loop)
  unsigned short* xp_h  = hm_h;
  unsigned short* xp_l  = hm_h + (size_t)2048*768;
  unsigned short* pem_h = hm_l;
  unsigned short* pem_l = hm_l + (size_t)2048*128;

  // patch embed
  k_patchify<<<6144, 256, 0, stream>>>(x, xp_h, xp_l);
  gemm_split<2><<<dim3(1, 16), 256, 0, stream>>>(xp_h, xp_l, pe1_w, nullptr, pem_h, pem_l, 128, 768, pe1_b, nullptr, 0);
  gemm_split<1><<<dim3(6, 16), 256, 0, stream>>>(pem_h, pem_l, pe2_w, xbuf, nullptr, nullptr, 768, 128, pe2_b, nullptr, 0);
  // conditioning
  k_cond<<<8, 256, 0, stream>>>(t, task_id, mod_id, t1_w, t1_b, t2_w, t2_b, task_tab, mod_tab, cbuf);

  for (int l = 0; l < 4; l++){
    k_mod<<<dim3(18, 8), 256, 0, stream>>>(cbuf, ada_w + (size_t)l*768*4608, ada_b + (size_t)l*4608, mod, 4608);
    // attention branch
    k_rms_mod<<<2048, 256, 0, stream>>>(xbuf, hh, hh_h, hh_l, n1_w + l*768, mod + 0, mod + 768, 4608);
    gemm_split<0><<<dim3(18, 16), 256, 0, stream>>>(hh_h, hh_l, qkv_w + (size_t)l*768*2304, qkv, nullptr, nullptr, 2304, 768, nullptr, nullptr, 0);
    k_qkv_prep<<<2048, 256, 0, stream>>>(qkv, qn_w + l*64, kn_w + l*64);
    k_attn<<<dim3(256, 12, 8), 256, 0, stream>>>(qkv, attn_h, attn_l);
    gemm_split<3><<<dim3(6, 16), 256, 0, stream>>>(attn_h, attn_l, proj_w + (size_t)l*768*768, xbuf, nullptr, nullptr, 768, 768, nullptr, mod + 2*768, 4608);
    // MoE branch
    k_rms_mod<<<2048, 256, 0, stream>>>(xbuf, hh, hh_h, hh_l, n2_w + l*768, mod + 3*768, mod + 4*768, 4608);
    hipMemsetAsync(counts, 0, 8*sizeof(int), stream);
    k_router<<<512, 256, 0, stream>>>(hh, rt_w + (size_t)l*768*8, counts, list, gate_slot);
    moe_gemm1_split<<<dim3(16, 128), 256, 0, stream>>>(hh_h, hh_l, w1, w3, counts, list, hm_h, hm_l, l);
    moe_gemm2_split<<<dim3(6, 128), 256, 0, stream>>>(hm_h, hm_l, w2, counts, list, y_slot, gate_slot, l);
    k_combine<<<6144, 256, 0, stream>>>(xbuf, y_slot, mod + 5*768);
  }

  // final layer
  k_mod<<<dim3(6, 8), 256, 0, stream>>>(cbuf, fada_w, fada_b, fmod, 1536);
  k_rms_mod<<<2048, 256, 0, stream>>>(xbuf, hh, hh_h, hh_l, fn_w, fmod + 0, fmod + 768, 1536);
  gemm_split<1><<<dim3(6, 16), 256, 0, stream>>>(hh_h, hh_l, fp_w, (float*)d_out, nullptr, nullptr, 768, 768, fp_b, nullptr, 0);
}

// Round 5
// 2844.142 us; speedup vs baseline: 1.8334x; 1.3443x over previous
//
#include <hip/hip_runtime.h>
#include <hip/hip_bf16.h>
#include <math.h>

typedef __bf16 bf16x8 __attribute__((ext_vector_type(8)));
typedef float f32x4 __attribute__((ext_vector_type(4)));
typedef unsigned short ushort;

__device__ __forceinline__ float siluf(float x){ return x / (1.0f + expf(-x)); }
__device__ __forceinline__ float geluf(float x){ return 0.5f*x*(1.0f+erff(x*0.70710678118654752f)); }

// exact truncation split: f = hi + lo with hi,lo bf16 (trunc)
__device__ __forceinline__ void split1(float f, ushort& hi, ushort& lo){
  union { float f; unsigned int u; } a; a.f = f;
  unsigned int h = a.u & 0xffff0000u;
  hi = (ushort)(h >> 16);
  union { unsigned int u; float f; } hf; hf.u = h;
  union { float f; unsigned int u; } l; l.f = f - hf.f;
  lo = (ushort)(l.u >> 16);
}
__device__ __forceinline__ void split2(float f0, float f1, unsigned int& hi, unsigned int& lo){
  union { float f; unsigned int u; } a, b; a.f = f0; b.f = f1;
  unsigned int h0 = a.u & 0xffff0000u, h1 = b.u & 0xffff0000u;
  hi = (h0 >> 16) | h1;
  union { unsigned int u; float f; } hf0, hf1; hf0.u = h0; hf1.u = h1;
  union { float f; unsigned int u; } l0, l1; l0.f = f0 - hf0.f; l1.f = f1 - hf1.f;
  lo = (l0.u >> 16) | (l1.u & 0xffff0000u);
}
__device__ __forceinline__ ushort f2bf(float f){
  union { float f; unsigned int u; } v; v.f = f;
  unsigned int r = v.u + 0x7fffu + ((v.u >> 16) & 1u);
  return (ushort)(r >> 16);
}

// ---------------- patchify -> split bf16 (T,768), feature order (c,ph,pw)
__global__ void k_patchify(const float* __restrict__ x,
                           ushort* __restrict__ xh, ushort* __restrict__ xl){
  int idx = blockIdx.x*256 + threadIdx.x;
  int t = idx / 768, f = idx % 768;
  int b = t >> 8, n = t & 255;
  int gh = n >> 4, gw = n & 15;
  int c = f >> 8, r = f & 255;
  int ph = r >> 4, pw = r & 15;
  float v = x[(((size_t)(b*3 + c)*256) + gh*16 + ph)*256 + gw*16 + pw];
  ushort h, l; split1(v, h, l);
  xh[idx] = h; xl[idx] = l;
}

// ---------------- timestep + task/modality conditioning -> c (8,768)
__global__ __launch_bounds__(256) void k_cond(const float* __restrict__ t,
    const int* __restrict__ task_id, const int* __restrict__ mod_id,
    const float* __restrict__ t1w, const float* __restrict__ t1b,
    const float* __restrict__ t2w, const float* __restrict__ t2b,
    const float* __restrict__ task_tab, const float* __restrict__ mod_tab,
    float* __restrict__ c){
  __shared__ float te[256];
  __shared__ float tm[768];
  int b = blockIdx.x, tid = threadIdx.x;
  float tv = t[b];
  int i = tid & 127;
  float freq = expf(-9.210340371976184f * (float)i / 128.0f);
  float arg = tv * freq;
  te[tid] = (tid < 128) ? cosf(arg) : sinf(arg);
  __syncthreads();
  for (int d = tid; d < 768; d += 256){
    float acc = t1b[d];
    for (int k = 0; k < 256; k++) acc += te[k]*t1w[k*768+d];
    tm[d] = siluf(acc);
  }
  __syncthreads();
  for (int d = tid; d < 768; d += 256){
    float acc = t2b[d];
    for (int k = 0; k < 768; k++) acc += tm[k]*t2w[k*768+d];
    c[b*768+d] = acc + task_tab[task_id[b]*768+d] + mod_tab[mod_id[b]*768+d];
  }
}

// ---------------- out[b][n] = bias[n] + sum_k silu(c[b][k]) * W[k][n]
__global__ __launch_bounds__(256) void k_mod(const float* __restrict__ c,
    const float* __restrict__ W, const float* __restrict__ bias,
    float* __restrict__ out, int N){
  __shared__ float sc[768];
  int b = blockIdx.y, tid = threadIdx.x;
  for (int k = tid; k < 768; k += 256) sc[k] = siluf(c[b*768+k]);
  __syncthreads();
  int n = blockIdx.x*256 + tid;
  float acc = bias[n];
  for (int k = 0; k < 768; k++) acc += sc[k]*W[(size_t)k*N + n];
  out[(size_t)b*N + n] = acc;
}

// ---------------- rmsnorm + modulate -> fp32 + split bf16
__global__ __launch_bounds__(256) void k_rms_mod(const float* __restrict__ x,
    float* __restrict__ out, ushort* __restrict__ oh, ushort* __restrict__ ol,
    const float* __restrict__ w,
    const float* __restrict__ shift, const float* __restrict__ scale, int mstride){
  __shared__ float red[256];
  int t = blockIdx.x, tid = threadIdx.x;
  float v0 = x[t*768 + tid], v1 = x[t*768 + 256 + tid], v2 = x[t*768 + 512 + tid];
  red[tid] = v0*v0 + v1*v1 + v2*v2;
  __syncthreads();
  for (int s2 = 128; s2 > 0; s2 >>= 1){ if (tid < s2) red[tid] += red[tid+s2]; __syncthreads(); }
  float r = rsqrtf(red[0]/768.0f + 1e-6f);
  int b = t >> 8;
  const float* sh = shift + (size_t)b*mstride;
  const float* scp = scale + (size_t)b*mstride;
  float o0 = v0*r*w[tid]    *(1.0f+scp[tid])     + sh[tid];
  float o1 = v1*r*w[tid+256]*(1.0f+scp[tid+256]) + sh[tid+256];
  float o2 = v2*r*w[tid+512]*(1.0f+scp[tid+512]) + sh[tid+512];
  out[t*768 + tid] = o0; out[t*768 + 256 + tid] = o1; out[t*768 + 512 + tid] = o2;
  ushort h, l;
  split1(o0, h, l); oh[t*768 + tid]       = h; ol[t*768 + tid]       = l;
  split1(o1, h, l); oh[t*768 + 256 + tid] = h; ol[t*768 + 256 + tid] = l;
  split1(o2, h, l); oh[t*768 + 512 + tid] = h; ol[t*768 + 512 + tid] = l;
}

// ---------------- q/k head-rms + 2D RoPE -> bf16 head-major qb/kb [bh][n][d]
// q additionally scaled by 1/sqrt(64) = 0.125
__global__ __launch_bounds__(256) void k_qkv_prep(const float* __restrict__ qkv,
    ushort* __restrict__ qb, ushort* __restrict__ kb,
    const float* __restrict__ qnw, const float* __restrict__ knw){
  int t = blockIdx.x;
  int wid = threadIdx.x >> 6, lane = threadIdx.x & 63;
  int n = t & 255, b = t >> 8;
  float phc = (float)(n >> 4), pwc = (float)(n & 15);
  int j = (lane & 31) >> 1;
  float freq = expf(-9.210340371976184f * (float)j / 16.0f);
  float ang = ((lane < 32) ? phc : pwc) * freq;
  float ca = cosf(ang), sa = sinf(ang);
  for (int r = wid; r < 24; r += 4){
    int isK = (r >= 12);
    int h = isK ? r - 12 : r;
    const float* p = qkv + (size_t)t*2304 + (isK ? 768 : 0) + h*64 + lane;
    float v = *p;
    float ss = v*v;
    #pragma unroll
    for (int off = 32; off; off >>= 1) ss += __shfl_xor(ss, off);
    float rr = rsqrtf(ss/64.0f + 1e-6f);
    float w = isK ? knw[lane] : qnw[lane];
    float xn = v*rr*w;
    float partner = __shfl_xor(xn, 1);
    float xr = (lane & 1) ? partner : -partner;
    float res = xn*ca + xr*sa;
    if (!isK) res *= 0.125f;
    ushort* dst = (isK ? kb : qb) + ((size_t)(b*12 + h))*16384 + n*64 + lane;
    *dst = f2bf(res);
  }
}

// ---------------- V transpose: qkv fp32 (T,2304) -> vt bf16 [bh][d=64][n=256]
__global__ __launch_bounds__(256) void k_vtrans(const float* __restrict__ qkv,
                                                ushort* __restrict__ vt){
  __shared__ float lds[64][65];
  int bh = blockIdx.x; int b = bh/12, h = bh%12;
  int tid = threadIdx.x;
  for (int p = 0; p < 4; p++){
    int n0 = p*64;
    __syncthreads();
    #pragma unroll
    for (int i = 0; i < 16; i++){
      int tt = i*4 + (tid>>6);
      int d = tid&63;
      lds[tt][d] = qkv[(size_t)(b*256 + n0 + tt)*2304 + 1536 + h*64 + d];
    }
    __syncthreads();
    #pragma unroll
    for (int i = 0; i < 16; i++){
      int d = i*4 + (tid>>6);
      int nn = tid&63;
      vt[(size_t)bh*16384 + d*256 + n0 + nn] = f2bf(lds[nn][d]);
    }
  }
}

// ---------------- fused MFMA attention: grid (qt=4, bh=96), 256 thr / 4 waves.
// Each wave: 16 q-rows. S=QK^T (fp32 acc), softmax in-reg, P->bf16 via LDS, O=PV.
#define KP 72     // K LDS row pad (u16)
#define VP 264    // Vt / P LDS row pad (u16)
__global__ __launch_bounds__(256) void k_fattn(
    const ushort* __restrict__ qb, const ushort* __restrict__ kb,
    const ushort* __restrict__ vt,
    ushort* __restrict__ oh, ushort* __restrict__ ol){
  __shared__ ushort ksh[256*KP];
  __shared__ ushort vsh[64*VP];
  __shared__ ushort psh[4][16*VP];
  int qt = blockIdx.x, bh = blockIdx.y;
  int b = bh/12, h = bh%12;
  int tid = threadIdx.x;
  // stage K [256][64] -> ksh, 16B chunks
  #pragma unroll
  for (int it = 0; it < 8; it++){
    int idx = it*256 + tid;
    int row = idx >> 3, ch = idx & 7;
    *(uint4*)&ksh[row*KP + ch*8] = *(const uint4*)&kb[(size_t)bh*16384 + row*64 + ch*8];
  }
  // stage Vt [64][256] -> vsh
  #pragma unroll
  for (int it = 0; it < 8; it++){
    int idx = it*256 + tid;
    int row = idx >> 5, ch = idx & 31;
    *(uint4*)&vsh[row*VP + ch*8] = *(const uint4*)&vt[(size_t)bh*16384 + row*256 + ch*8];
  }
  __syncthreads();
  int lane = tid & 63, w = tid >> 6;
  int lr = lane & 15, lg = lane >> 4;
  int q0 = qt*64 + w*16;
  // Q fragments from global
  bf16x8 af0 = *(const bf16x8*)&qb[(size_t)bh*16384 + (q0 + lr)*64 + lg*8];
  bf16x8 af1 = *(const bf16x8*)&qb[(size_t)bh*16384 + (q0 + lr)*64 + lg*8 + 32];
  // S = Q K^T  (scale already folded into q)
  f32x4 s[16];
  #pragma unroll
  for (int nt = 0; nt < 16; nt++){
    f32x4 z = {};
    z = __builtin_amdgcn_mfma_f32_16x16x32_bf16(af0, *(const bf16x8*)&ksh[(nt*16 + lr)*KP + lg*8], z, 0, 0, 0);
    z = __builtin_amdgcn_mfma_f32_16x16x32_bf16(af1, *(const bf16x8*)&ksh[(nt*16 + lr)*KP + lg*8 + 32], z, 0, 0, 0);
    s[nt] = z;
  }
  // softmax over 256 cols; lane holds rows lg*4+r, col nt*16+lr
  float inv[4];
  #pragma unroll
  for (int r = 0; r < 4; r++){
    float m = -1e30f;
    #pragma unroll
    for (int nt = 0; nt < 16; nt++) m = fmaxf(m, s[nt][r]);
    #pragma unroll
    for (int off = 1; off < 16; off <<= 1) m = fmaxf(m, __shfl_xor(m, off));
    float sum = 0.f;
    #pragma unroll
    for (int nt = 0; nt < 16; nt++){ float p = expf(s[nt][r] - m); s[nt][r] = p; sum += p; }
    #pragma unroll
    for (int off = 1; off < 16; off <<= 1) sum += __shfl_xor(sum, off);
    inv[r] = 1.0f/sum;
  }
  // P -> LDS (bf16), row = q-row-in-tile, col = key
  #pragma unroll
  for (int nt = 0; nt < 16; nt++){
    #pragma unroll
    for (int r = 0; r < 4; r++)
      psh[w][(lg*4 + r)*VP + nt*16 + lr] = f2bf(s[nt][r]);
  }
  __syncthreads();
  // O = P V : A = psh rows (q), B = vsh rows (d)
  f32x4 o[4] = {};
  #pragma unroll
  for (int dt = 0; dt < 4; dt++){
    #pragma unroll
    for (int k0 = 0; k0 < 8; k0++){
      bf16x8 pa = *(const bf16x8*)&psh[w][lr*VP + lg*8 + k0*32];
      bf16x8 bv = *(const bf16x8*)&vsh[(dt*16 + lr)*VP + lg*8 + k0*32];
      o[dt] = __builtin_amdgcn_mfma_f32_16x16x32_bf16(pa, bv, o[dt], 0, 0, 0);
    }
  }
  // write out (split bf16): token row, col = h*64 + dt*16 + lr
  #pragma unroll
  for (int dt = 0; dt < 4; dt++){
    #pragma unroll
    for (int r = 0; r < 4; r++){
      int token = b*256 + q0 + lg*4 + r;
      int col = h*64 + dt*16 + lr;
      ushort hh, ll; split1(o[dt][r]*inv[lg*0 + r], hh, ll);
      oh[(size_t)token*768 + col] = hh;
      ol[(size_t)token*768 + col] = ll;
    }
  }
}

// ---------------- router (fp32 hh)
__global__ __launch_bounds__(256) void k_router(const float* __restrict__ hh,
    const float* __restrict__ rw, int* __restrict__ counts,
    int* __restrict__ list, float* __restrict__ gate_slot){
  int wid = threadIdx.x >> 6, lane = threadIdx.x & 63;
  int t = blockIdx.x*4 + wid;
  float acc[8] = {0,0,0,0,0,0,0,0};
  for (int k = lane; k < 768; k += 64){
    float a = hh[t*768 + k];
    #pragma unroll
    for (int e = 0; e < 8; e++) acc[e] += a * rw[k*8 + e];
  }
  #pragma unroll
  for (int e = 0; e < 8; e++){
    #pragma unroll
    for (int off = 32; off; off >>= 1) acc[e] += __shfl_xor(acc[e], off);
  }
  if (lane == 0){
    float v1 = -1e30f, v2 = -1e30f; int e1 = 0, e2 = 0;
    #pragma unroll
    for (int e = 0; e < 8; e++){
      float v = acc[e];
      if (v > v1){ v2 = v1; e2 = e1; v1 = v; e1 = e; }
      else if (v > v2){ v2 = v; e2 = e; }
    }
    float g1 = 1.0f/(1.0f+expf(v2-v1));
    float g2 = 1.0f - g1;
    int p1 = atomicAdd(&counts[e1], 1); list[e1*2048 + p1] = t*2;
    int p2 = atomicAdd(&counts[e2], 1); list[e2*2048 + p2] = t*2+1;
    gate_slot[t*2] = g1; gate_slot[t*2+1] = g2;
  }
}

// =================== split-bf16 MFMA GEMM (3-pass), 128x128 tile, 4 waves @64x64
#define LDK 40
template<int EPI>
__global__ __launch_bounds__(256) void gemm_split(
    const ushort* __restrict__ Ahi, const ushort* __restrict__ Alo,
    const float* __restrict__ B,
    float* __restrict__ C, ushort* __restrict__ Chi, ushort* __restrict__ Clo,
    int N, int K,
    const float* __restrict__ bias, const float* __restrict__ gate, int gstride){
  __shared__ ushort AsH[128*LDK], AsL[128*LDK];
  __shared__ ushort BsH[128*LDK], BsL[128*LDK];
  int tid = threadIdx.x;
  int m0 = blockIdx.y*128, n0 = blockIdx.x*128;
  int lane = tid & 63, wid = tid >> 6;
  int wr = wid >> 1, wc = wid & 1;
  int lr = lane & 15, lg = lane >> 4;
  int ar = tid & 127, ah = tid >> 7;
  int bn = tid & 127, bh = tid >> 7;
  size_t aoff = (size_t)(m0 + ar)*K + ah*16;
  f32x4 acc[4][4] = {};
  for (int k0 = 0; k0 < K; k0 += 32){
    { const uint4* ph = (const uint4*)(Ahi + aoff + k0);
      const uint4* pl = (const uint4*)(Alo + aoff + k0);
      uint4* qh = (uint4*)&AsH[ar*LDK + ah*16];
      uint4* ql = (uint4*)&AsL[ar*LDK + ah*16];
      qh[0] = ph[0]; qh[1] = ph[1]; ql[0] = pl[0]; ql[1] = pl[1]; }
    { const float* bp = B + (size_t)(k0 + bh*16)*N + n0 + bn;
      unsigned int* qh = (unsigned int*)&BsH[bn*LDK + bh*16];
      unsigned int* ql = (unsigned int*)&BsL[bn*LDK + bh*16];
      #pragma unroll
      for (int m2 = 0; m2 < 8; m2++){
        unsigned int h, l;
        split2(bp[(size_t)(2*m2)*N], bp[(size_t)(2*m2+1)*N], h, l);
        qh[m2] = h; ql[m2] = l;
      }
    }
    __syncthreads();
    bf16x8 aH[4], aL[4];
    #pragma unroll
    for (int mf = 0; mf < 4; mf++){
      aH[mf] = *(const bf16x8*)&AsH[(wr*64 + mf*16 + lr)*LDK + lg*8];
      aL[mf] = *(const bf16x8*)&AsL[(wr*64 + mf*16 + lr)*LDK + lg*8];
    }
    #pragma unroll
    for (int nf = 0; nf < 4; nf++){
      bf16x8 bH = *(const bf16x8*)&BsH[(wc*64 + nf*16 + lr)*LDK + lg*8];
      bf16x8 bL = *(const bf16x8*)&BsL[(wc*64 + nf*16 + lr)*LDK + lg*8];
      #pragma unroll
      for (int mf = 0; mf < 4; mf++){
        acc[mf][nf] = __builtin_amdgcn_mfma_f32_16x16x32_bf16(aH[mf], bH, acc[mf][nf], 0, 0, 0);
        acc[mf][nf] = __builtin_amdgcn_mfma_f32_16x16x32_bf16(aH[mf], bL, acc[mf][nf], 0, 0, 0);
        acc[mf][nf] = __builtin_amdgcn_mfma_f32_16x16x32_bf16(aL[mf], bH, acc[mf][nf], 0, 0, 0);
      }
    }
    __syncthreads();
  }
  #pragma unroll
  for (int mf = 0; mf < 4; mf++){
    #pragma unroll
    for (int nf = 0; nf < 4; nf++){
      #pragma unroll
      for (int r = 0; r < 4; r++){
        int m = m0 + wr*64 + mf*16 + lg*4 + r;
        int n = n0 + wc*64 + nf*16 + lr;
        float v = acc[mf][nf][r];
        if (EPI == 1){ C[(size_t)m*N + n] = v + bias[n]; }
        else if (EPI == 2){
          ushort h, l; split1(geluf(v + bias[n]), h, l);
          Chi[(size_t)m*N + n] = h; Clo[(size_t)m*N + n] = l;
        }
        else if (EPI == 3){ C[(size_t)m*N + n] += gate[(size_t)(m >> 8)*gstride + n]*v; }
        else { C[(size_t)m*N + n] = v; }
      }
    }
  }
}

// =================== MoE grouped GEMM 1 (split): h_mid[slot] = silu(A@w1)*(A@w3)
__global__ __launch_bounds__(256) void moe_gemm1_split(
    const ushort* __restrict__ Ahi, const ushort* __restrict__ Alo,
    const float* __restrict__ w1, const float* __restrict__ w3,
    const int* __restrict__ counts, const int* __restrict__ list,
    ushort* __restrict__ mh, ushort* __restrict__ ml, int layer){
  int e = blockIdx.y >> 4, mt = blockIdx.y & 15;
  int count = counts[e];
  if (mt*128 >= count) return;
  __shared__ ushort AsH[128*LDK], AsL[128*LDK];
  __shared__ ushort B1H[128*LDK], B1L[128*LDK];
  __shared__ ushort B3H[128*LDK], B3L[128*LDK];
  __shared__ int slotArr[128];
  int tid = threadIdx.x;
  int n0 = blockIdx.x*128;
  const float* B1 = w1 + ((size_t)(layer*8 + e))*768*2048;
  const float* B3 = w3 + ((size_t)(layer*8 + e))*768*2048;
  if (tid < 128){
    int ml2 = mt*128 + tid;
    slotArr[tid] = (ml2 < count) ? list[e*2048 + ml2] : -1;
  }
  __syncthreads();
  int lane = tid & 63, wid = tid >> 6;
  int wr = wid >> 1, wc = wid & 1;
  int lr = lane & 15, lg = lane >> 4;
  int ar = tid & 127, ah = tid >> 7;
  int bn = tid & 127, bh = tid >> 7;
  int s0 = slotArr[ar]; int tok = (s0 < 0) ? 0 : (s0 >> 1);
  size_t aoff = (size_t)tok*768 + ah*16;
  f32x4 acc1[4][4] = {}, acc3[4][4] = {};
  for (int k0 = 0; k0 < 768; k0 += 32){
    { const uint4* ph = (const uint4*)(Ahi + aoff + k0);
      const uint4* pl = (const uint4*)(Alo + aoff + k0);
      uint4* qh = (uint4*)&AsH[ar*LDK + ah*16];
      uint4* ql = (uint4*)&AsL[ar*LDK + ah*16];
      qh[0] = ph[0]; qh[1] = ph[1]; ql[0] = pl[0]; ql[1] = pl[1]; }
    { const float* bp1 = B1 + (size_t)(k0 + bh*16)*2048 + n0 + bn;
      const float* bp3 = B3 + (size_t)(k0 + bh*16)*2048 + n0 + bn;
      unsigned int* q1h = (unsigned int*)&B1H[bn*LDK + bh*16];
      unsigned int* q1l = (unsigned int*)&B1L[bn*LDK + bh*16];
      unsigned int* q3h = (unsigned int*)&B3H[bn*LDK + bh*16];
      unsigned int* q3l = (unsigned int*)&B3L[bn*LDK + bh*16];
      #pragma unroll
      for (int m2 = 0; m2 < 8; m2++){
        unsigned int h, l;
        split2(bp1[(size_t)(2*m2)*2048], bp1[(size_t)(2*m2+1)*2048], h, l);
        q1h[m2] = h; q1l[m2] = l;
        split2(bp3[(size_t)(2*m2)*2048], bp3[(size_t)(2*m2+1)*2048], h, l);
        q3h[m2] = h; q3l[m2] = l;
      }
    }
    __syncthreads();
    bf16x8 aH[4], aL[4];
    #pragma unroll
    for (int mf = 0; mf < 4; mf++){
      aH[mf] = *(const bf16x8*)&AsH[(wr*64 + mf*16 + lr)*LDK + lg*8];
      aL[mf] = *(const bf16x8*)&AsL[(wr*64 + mf*16 + lr)*LDK + lg*8];
    }
    #pragma unroll
    for (int nf = 0; nf < 4; nf++){
      bf16x8 b1h = *(const bf16x8*)&B1H[(wc*64 + nf*16 + lr)*LDK + lg*8];
      bf16x8 b1l = *(const bf16x8*)&B1L[(wc*64 + nf*16 + lr)*LDK + lg*8];
      bf16x8 b3h = *(const bf16x8*)&B3H[(wc*64 + nf*16 + lr)*LDK + lg*8];
      bf16x8 b3l = *(const bf16x8*)&B3L[(wc*64 + nf*16 + lr)*LDK + lg*8];
      #pragma unroll
      for (int mf = 0; mf < 4; mf++){
        acc1[mf][nf] = __builtin_amdgcn_mfma_f32_16x16x32_bf16(aH[mf], b1h, acc1[mf][nf], 0, 0, 0);
        acc1[mf][nf] = __builtin_amdgcn_mfma_f32_16x16x32_bf16(aH[mf], b1l, acc1[mf][nf], 0, 0, 0);
        acc1[mf][nf] = __builtin_amdgcn_mfma_f32_16x16x32_bf16(aL[mf], b1h, acc1[mf][nf], 0, 0, 0);
        acc3[mf][nf] = __builtin_amdgcn_mfma_f32_16x16x32_bf16(aH[mf], b3h, acc3[mf][nf], 0, 0, 0);
        acc3[mf][nf] = __builtin_amdgcn_mfma_f32_16x16x32_bf16(aH[mf], b3l, acc3[mf][nf], 0, 0, 0);
        acc3[mf][nf] = __builtin_amdgcn_mfma_f32_16x16x32_bf16(aL[mf], b3h, acc3[mf][nf], 0, 0, 0);
      }
    }
    __syncthreads();
  }
  #pragma unroll
  for (int mf = 0; mf < 4; mf++){
    #pragma unroll
    for (int nf = 0; nf < 4; nf++){
      #pragma unroll
      for (int r = 0; r < 4; r++){
        int row = wr*64 + mf*16 + lg*4 + r;
        int sl = slotArr[row];
        if (sl < 0) continue;
        int n = n0 + wc*64 + nf*16 + lr;
        float v = siluf(acc1[mf][nf][r]) * acc3[mf][nf][r];
        ushort h, l; split1(v, h, l);
        mh[(size_t)sl*2048 + n] = h; ml[(size_t)sl*2048 + n] = l;
      }
    }
  }
}

// =================== MoE grouped GEMM 2 (split): y_slot[slot] = gate[slot]*(h_mid[slot]@w2)
__global__ __launch_bounds__(256) void moe_gemm2_split(
    const ushort* __restrict__ Ahi, const ushort* __restrict__ Alo,
    const float* __restrict__ w2,
    const int* __restrict__ counts, const int* __restrict__ list,
    float* __restrict__ y_slot, const float* __restrict__ gate_slot, int layer){
  int e = blockIdx.y >> 4, mt = blockIdx.y & 15;
  int count = counts[e];
  if (mt*128 >= count) return;
  __shared__ ushort AsH[128*LDK], AsL[128*LDK];
  __shared__ ushort BsH[128*LDK], BsL[128*LDK];
  __shared__ int slotArr[128];
  int tid = threadIdx.x;
  int n0 = blockIdx.x*128;
  const float* B = w2 + ((size_t)(layer*8 + e))*2048*768;
  if (tid < 128){
    int ml2 = mt*128 + tid;
    slotArr[tid] = (ml2 < count) ? list[e*2048 + ml2] : -1;
  }
  __syncthreads();
  int lane = tid & 63, wid = tid >> 6;
  int wr = wid >> 1, wc = wid & 1;
  int lr = lane & 15, lg = lane >> 4;
  int ar = tid & 127, ah = tid >> 7;
  int bn = tid & 127, bh = tid >> 7;
  int s0 = slotArr[ar]; int arow = (s0 < 0) ? 0 : s0;
  size_t aoff = (size_t)arow*2048 + ah*16;
  f32x4 acc[4][4] = {};
  for (int k0 = 0; k0 < 2048; k0 += 32){
    { const uint4* ph = (const uint4*)(Ahi + aoff + k0);
      const uint4* pl = (const uint4*)(Alo + aoff + k0);
      uint4* qh = (uint4*)&AsH[ar*LDK + ah*16];
      uint4* ql = (uint4*)&AsL[ar*LDK + ah*16];
      qh[0] = ph[0]; qh[1] = ph[1]; ql[0] = pl[0]; ql[1] = pl[1]; }
    { const float* bp = B + (size_t)(k0 + bh*16)*768 + n0 + bn;
      unsigned int* qh = (unsigned int*)&BsH[bn*LDK + bh*16];
      unsigned int* ql = (unsigned int*)&BsL[bn*LDK + bh*16];
      #pragma unroll
      for (int m2 = 0; m2 < 8; m2++){
        unsigned int h, l;
        split2(bp[(size_t)(2*m2)*768], bp[(size_t)(2*m2+1)*768], h, l);
        qh[m2] = h; ql[m2] = l;
      }
    }
    __syncthreads();
    bf16x8 aH[4], aL[4];
    #pragma unroll
    for (int mf = 0; mf < 4; mf++){
      aH[mf] = *(const bf16x8*)&AsH[(wr*64 + mf*16 + lr)*LDK + lg*8];
      aL[mf] = *(const bf16x8*)&AsL[(wr*64 + mf*16 + lr)*LDK + lg*8];
    }
    #pragma unroll
    for (int nf = 0; nf < 4; nf++){
      bf16x8 bH = *(const bf16x8*)&BsH[(wc*64 + nf*16 + lr)*LDK + lg*8];
      bf16x8 bL = *(const bf16x8*)&BsL[(wc*64 + nf*16 + lr)*LDK + lg*8];
      #pragma unroll
      for (int mf = 0; mf < 4; mf++){
        acc[mf][nf] = __builtin_amdgcn_mfma_f32_16x16x32_bf16(aH[mf], bH, acc[mf][nf], 0, 0, 0);
        acc[mf][nf] = __builtin_amdgcn_mfma_f32_16x16x32_bf16(aH[mf], bL, acc[mf][nf], 0, 0, 0);
        acc[mf][nf] = __builtin_amdgcn_mfma_f32_16x16x32_bf16(aL[mf], bH, acc[mf][nf], 0, 0, 0);
      }
    }
    __syncthreads();
  }
  #pragma unroll
  for (int mf = 0; mf < 4; mf++){
    #pragma unroll
    for (int nf = 0; nf < 4; nf++){
      #pragma unroll
      for (int r = 0; r < 4; r++){
        int row = wr*64 + mf*16 + lg*4 + r;
        int sl = slotArr[row];
        if (sl < 0) continue;
        int n = n0 + wc*64 + nf*16 + lr;
        y_slot[(size_t)sl*768 + n] = gate_slot[sl]*acc[mf][nf][r];
      }
    }
  }
}

// ---------------- combine MoE: x += gp[b] * (y_slot[2t] + y_slot[2t+1])
__global__ void k_combine(float* __restrict__ x, const float* __restrict__ y_slot,
                          const float* __restrict__ gp){
  int idx = blockIdx.x*256 + threadIdx.x;
  int t = idx / 768, d = idx % 768;
  int b = t >> 8;
  x[idx] += gp[(size_t)b*4608 + d]*(y_slot[(size_t)(t*2)*768 + d] + y_slot[(size_t)(t*2+1)*768 + d]);
}

extern "C" void kernel_launch(void* const* d_in, const int* in_sizes, int n_in,
                              void* d_out, int out_size, void* d_ws, size_t ws_size,
                              hipStream_t stream){
  const float* x       = (const float*)d_in[0];
  const float* t       = (const float*)d_in[1];
  const int*   task_id = (const int*)d_in[2];
  const int*   mod_id  = (const int*)d_in[3];
  const float* pe1_w   = (const float*)d_in[4];
  const float* pe1_b   = (const float*)d_in[5];
  const float* pe2_w   = (const float*)d_in[6];
  const float* pe2_b   = (const float*)d_in[7];
  const float* t1_w    = (const float*)d_in[8];
  const float* t1_b    = (const float*)d_in[9];
  const float* t2_w    = (const float*)d_in[10];
  const float* t2_b    = (const float*)d_in[11];
  const float* task_tab= (const float*)d_in[12];
  const float* mod_tab = (const float*)d_in[13];
  const float* qkv_w   = (const float*)d_in[14];
  const float* proj_w  = (const float*)d_in[15];
  const float* qn_w    = (const float*)d_in[16];
  const float* kn_w    = (const float*)d_in[17];
  const float* n1_w    = (const float*)d_in[18];
  const float* n2_w    = (const float*)d_in[19];
  const float* ada_w   = (const float*)d_in[20];
  const float* ada_b   = (const float*)d_in[21];
  const float* rt_w    = (const float*)d_in[22];
  const float* w1      = (const float*)d_in[23];
  const float* w2      = (const float*)d_in[24];
  const float* w3      = (const float*)d_in[25];
  const float* fn_w    = (const float*)d_in[26];
  const float* fada_w  = (const float*)d_in[27];
  const float* fada_b  = (const float*)d_in[28];
  const float* fp_w    = (const float*)d_in[29];
  const float* fp_b    = (const float*)d_in[30];

  float* ws = (float*)d_ws;
  float* xbuf    = ws;  ws += (size_t)2048*768;
  float* hh      = ws;  ws += (size_t)2048*768;
  float* qkv     = ws;  ws += (size_t)2048*2304;
  float* y_slot  = ws;  ws += (size_t)4096*768;
  float* cbuf    = ws;  ws += 8*768;
  float* mod     = ws;  ws += 8*4608;
  float* fmod    = ws;  ws += 8*1536;
  float* gate_slot = ws; ws += 4096;
  int* counts = (int*)ws; ws += 8;
  int* list   = (int*)ws; ws += 8*2048;
  ws += 8;
  ushort* us = (ushort*)ws;
  ushort* hh_h   = us; us += (size_t)2048*768;
  ushort* hh_l   = us; us += (size_t)2048*768;
  ushort* hm_h   = us; us += (size_t)4096*2048;
  ushort* hm_l   = us; us += (size_t)4096*2048;
  ushort* attn_h = us; us += (size_t)2048*768;
  ushort* attn_l = us; us += (size_t)2048*768;
  ushort* qb     = us; us += (size_t)96*16384;
  ushort* kb     = us; us += (size_t)96*16384;
  ushort* vt     = us; us += (size_t)96*16384;
  // pre-loop scratch aliased onto h_mid (only used before layer loop)
  ushort* xp_h  = hm_h;
  ushort* xp_l  = hm_h + (size_t)2048*768;
  ushort* pem_h = hm_l;
  ushort* pem_l = hm_l + (size_t)2048*128;

  // patch embed
  k_patchify<<<6144, 256, 0, stream>>>(x, xp_h, xp_l);
  gemm_split<2><<<dim3(1, 16), 256, 0, stream>>>(xp_h, xp_l, pe1_w, nullptr, pem_h, pem_l, 128, 768, pe1_b, nullptr, 0);
  gemm_split<1><<<dim3(6, 16), 256, 0, stream>>>(pem_h, pem_l, pe2_w, xbuf, nullptr, nullptr, 768, 128, pe2_b, nullptr, 0);
  // conditioning
  k_cond<<<8, 256, 0, stream>>>(t, task_id, mod_id, t1_w, t1_b, t2_w, t2_b, task_tab, mod_tab, cbuf);

  for (int l = 0; l < 4; l++){
    k_mod<<<dim3(18, 8), 256, 0, stream>>>(cbuf, ada_w + (size_t)l*768*4608, ada_b + (size_t)l*4608, mod, 4608);
    // attention branch
    k_rms_mod<<<2048, 256, 0, stream>>>(xbuf, hh, hh_h, hh_l, n1_w + l*768, mod + 0, mod + 768, 4608);
    gemm_split<0><<<dim3(18, 16), 256, 0, stream>>>(hh_h, hh_l, qkv_w + (size_t)l*768*2304, qkv, nullptr, nullptr, 2304, 768, nullptr, nullptr, 0);
    k_qkv_prep<<<2048, 256, 0, stream>>>(qkv, qb, kb, qn_w + l*64, kn_w + l*64);
    k_vtrans<<<96, 256, 0, stream>>>(qkv, vt);
    k_fattn<<<dim3(4, 96), 256, 0, stream>>>(qb, kb, vt, attn_h, attn_l);
    gemm_split<3><<<dim3(6, 16), 256, 0, stream>>>(attn_h, attn_l, proj_w + (size_t)l*768*768, xbuf, nullptr, nullptr, 768, 768, nullptr, mod + 2*768, 4608);
    // MoE branch
    k_rms_mod<<<2048, 256, 0, stream>>>(xbuf, hh, hh_h, hh_l, n2_w + l*768, mod + 3*768, mod + 4*768, 4608);
    hipMemsetAsync(counts, 0, 8*sizeof(int), stream);
    k_router<<<512, 256, 0, stream>>>(hh, rt_w + (size_t)l*768*8, counts, list, gate_slot);
    moe_gemm1_split<<<dim3(16, 128), 256, 0, stream>>>(hh_h, hh_l, w1, w3, counts, list, hm_h, hm_l, l);
    moe_gemm2_split<<<dim3(6, 128), 256, 0, stream>>>(hm_h, hm_l, w2, counts, list, y_slot, gate_slot, l);
    k_combine<<<6144, 256, 0, stream>>>(xbuf, y_slot, mod + 5*768);
  }

  // final layer
  k_mod<<<dim3(6, 8), 256, 0, stream>>>(cbuf, fada_w, fada_b, fmod, 1536);
  k_rms_mod<<<2048, 256, 0, stream>>>(xbuf, hh, hh_h, hh_l, fn_w, fmod + 0, fmod + 768, 1536);
  gemm_split<1><<<dim3(6, 16), 256, 0, stream>>>(hh_h, hh_l, fp_w, (float*)d_out, nullptr, nullptr, 768, 768, fp_b, nullptr, 0);
}